// Round 10
// baseline (3104.316 us; speedup 1.0000x reference)
//
#include <hip/hip_runtime.h>
#include <stdint.h>

// ============================================================================
// 2-layer GRU decoder, B=128, T=512, H=256, heads 128/64/64 (concat=256).
// Persistent latency design + SPLIT-F16 precision (effectively fp32 matmuls):
//   A*W ~= Ah*Wh + (Al_s*Wh + Ah*Wl_s)/2048, lo-parts pre-scaled by 2^11.
// Round-9 exchange (round-6 structure + both overlaps):
//   * per-WAVE flags: each wave flags after ITS OWN vmcnt(0) drain -> no
//     pre-flag barrier. Consumer: wv0 polls all 64 cluster flags (lane-mapped,
//     one load + __all). All sync ops sc0 sc1 (r5: sc0-only is CU-scope).
//   * gh split across the drain: reg-only chains (m,c1) BETWEEN publish and
//     vmcnt(0) (hide store-ack; sched_barrier(0) pins them), c2+SCW AFTER the
//     flag store (hide flag propagation, as r6 did). 6 barriers/step (was 8).
//   * r7 lesson kept: flag always AFTER drain; no tagged/data polling (r4).
// ============================================================================

typedef __attribute__((ext_vector_type(8))) _Float16 half8;
typedef __attribute__((ext_vector_type(4))) float f32x4;
typedef __attribute__((ext_vector_type(4))) unsigned int u32x4;

// blob fragment-unit (16B) section bases: b=0 W', 1 Wih0, 2 Whh0, 3 Wih1, 4 Whh1
#define HIU(b,p,g)  ((unsigned)((b)*24576u + ((p)*3u+(g))*512u))
#define LOU(b,p,g)  ((unsigned)(122880u + (b)*24576u + ((p)*3u+(g))*512u))
#define HEADU(p)    ((unsigned)(245760u + (p)*512u))
#define NUNITS      253952u

// workspace offsets (bytes)
#define FLAGS_OFF 0u            // 8192 u32: flag (cl,blk,wv) at (cl*64+blk*4+wv)*16
#define PUB0_OFF  32768u        // 32768 u32 (hi|lo<<16)
#define PUB1_OFF  163840u
#define BP_OFF    294912u
#define BLOB_OFF  298496u
#define WS_NEEDED (BLOB_OFF + NUNITS*16u)

// LDS offsets (bytes)  — round-6 layout
#define HA_HI 0u
#define HA_LO 8192u
#define HB_HI 16384u
#define HB_LO 24576u
#define SCR   32768u        // 9 slots * 288 fp32 (17-stride pad) = 10368B
#define BIASO 43136u        // 256 floats
#define WLDS  44160u        // wv1..3: h1lo+h0lo (16KB each); head hi at +49152
#define LDS_TOTAL (44160u + 57344u)   // 101504 B

__device__ __forceinline__ uint16_t f2h_bits(float x) {
  _Float16 h = (_Float16)x;
  return __builtin_bit_cast(uint16_t, h);
}
__device__ __forceinline__ float sigmoidf_(float x) { return 1.f / (1.f + __expf(-x)); }

// system-scope (LLC) coherent store — validated rounds 3/6
__device__ __forceinline__ void st_cc_d(uint32_t* p, uint32_t v) {
  asm volatile("global_store_dword %0, %1, off sc0 sc1" :: "v"(p), "v"(v) : "memory");
}

// ---------------------------------------------------------------------------
// init1: W' = Wih0 @ Wcat written DIRECTLY as split-f16 blob (b=0 sections);
//        b' = bih0 + Wih0 . bcat -> bp.   (validated rounds 4/6)
// ---------------------------------------------------------------------------
__global__ void gru_init1(const float* __restrict__ Wih0, const float* __restrict__ Wn,
                          const float* __restrict__ Wd, const float* __restrict__ Wg,
                          const float* __restrict__ bn, const float* __restrict__ bd,
                          const float* __restrict__ bg, const float* __restrict__ bih0,
                          uint16_t* __restrict__ BW, float* __restrict__ bp)
{
  const int i = blockIdx.x;   // 0..767  (gate-major row of W')
  const int j = threadIdx.x;  // 0..255  (column)
  float acc = 0.f;
  for (int k = 0; k < 256; ++k) {
    float w = Wih0[i*256 + k];
    float c = (k < 128) ? Wn[k*256 + j] : (k < 192) ? Wd[(k-128)*256 + j] : Wg[(k-192)*256 + j];
    acc += w * c;
  }
  const uint32_t g = (uint32_t)i >> 8, p = ((uint32_t)i & 255u) >> 4, r = (uint32_t)i & 15u;
  const uint32_t kt = (uint32_t)j >> 5, c4 = ((uint32_t)j >> 3) & 3u, e = (uint32_t)j & 7u;
  const uint32_t base = ((p*3u + g)*512u + kt*64u + c4*16u + r)*8u + e;
  _Float16 hi = (_Float16)acc;
  BW[base] = __builtin_bit_cast(uint16_t, hi);
  BW[122880u*8u + base] = f2h_bits((acc - (float)hi) * 2048.f);
  if (j == 0) {
    float bb = bih0[i];
    for (int k = 0; k < 256; ++k) {
      float bc = (k < 128) ? bn[k] : (k < 192) ? bd[k-128] : bg[k-192];
      bb += Wih0[i*256 + k] * bc;
    }
    bp[i] = bb;
  }
}

// ---------------------------------------------------------------------------
// init2: split-f16 blobs for b=1..4 + head; b=0-range threads zero the 8192
// per-wave flags (system-scope stores; flags monotonic -> replay-safe).
// ---------------------------------------------------------------------------
__global__ void gru_init2(const float* __restrict__ Wih0, const float* __restrict__ Whh0,
                          const float* __restrict__ Wih1, const float* __restrict__ Whh1,
                          const float* __restrict__ Wn, const float* __restrict__ Wd,
                          const float* __restrict__ Wg,
                          uint32_t* __restrict__ flags, uint16_t* __restrict__ BW)
{
  const uint32_t u = blockIdx.x*256u + threadIdx.x;   // 0..253951
  const bool isB0 = (u < 24576u) || (u >= 122880u && u < 147456u);
  if (isB0) {
    const uint32_t zi = (u < 24576u) ? u : (u - 122880u + 24576u);  // 0..49151
    if (zi < 8192u) st_cc_d(flags + zi, 0u);
    return;
  }
  bool lo = false;
  const float* s;
  if (u < 245760u) {
    uint32_t v = u;
    if (v >= 122880u) { v -= 122880u; lo = true; }
    uint32_t b = v/24576u, rem = v%24576u;          // b in 1..4 here
    uint32_t p = rem/1536u, r2 = rem%1536u;
    uint32_t g = r2/512u,  r3 = r2%512u;
    uint32_t kt = r3>>6,   l = r3&63u;
    const float* W = (b==1)?Wih0:(b==2)?Whh0:(b==3)?Wih1:Whh1;
    s = W + (size_t)(g*256u + p*16u + (l&15u))*256u + kt*32u + (l>>4)*8u;
  } else {
    uint32_t rem = u - 245760u;
    uint32_t p = rem/512u, r3 = rem%512u;
    uint32_t kt = r3>>6,   l = r3&63u;
    uint32_t row = p*16u + (l&15u), k0 = kt*32u + (l>>4)*8u;
    s = (row < 128u) ? (Wn + (size_t)row*256u + k0)
      : (row < 192u) ? (Wd + (size_t)(row-128u)*256u + k0)
      :                (Wg + (size_t)(row-192u)*256u + k0);
  }
  u32x4 vv;
#pragma unroll
  for (int i = 0; i < 4; ++i) {
    float w0 = s[2*i], w1 = s[2*i+1];
    uint16_t b0, b1;
    if (!lo) { b0 = f2h_bits(w0); b1 = f2h_bits(w1); }
    else {
      float r0 = w0 - (float)((_Float16)w0);
      float r1 = w1 - (float)((_Float16)w1);
      b0 = f2h_bits(r0 * 2048.f); b1 = f2h_bits(r1 * 2048.f);
    }
    vv[i] = (uint32_t)b0 | ((uint32_t)b1 << 16);
  }
  *(u32x4*)(BW + (size_t)u * 8u) = vv;
}

// ---------------------------------------------------------------------------
// main persistent kernel: 128 blocks x 256 threads, 512 steps.
// ---------------------------------------------------------------------------
__launch_bounds__(256, 1)
__global__ void gru_main(const float* __restrict__ x0in,
                         const float* __restrict__ bih0, const float* __restrict__ bhh0,
                         const float* __restrict__ bih1, const float* __restrict__ bhh1,
                         const float* __restrict__ bn, const float* __restrict__ bd,
                         const float* __restrict__ bg, const float* __restrict__ bp,
                         const uint16_t* __restrict__ BW,
                         uint32_t* __restrict__ flags,
                         uint32_t* __restrict__ pub0, uint32_t* __restrict__ pub1,
                         float* __restrict__ out)
{
  extern __shared__ char smem[];
  const int tid  = threadIdx.x;
  const int lane = tid & 63;
  const int wv   = tid >> 6;
  const int cl   = blockIdx.x & 7;
  const int p    = blockIdx.x >> 3;

  // ---- biases -> LDS: [0)b' [48)bih0 [96)bhh0 [144)bih1 [192)bhh1 [240)bhead
  if (tid < 48) {
    const int gi = (tid >> 4)*256 + p*16 + (tid & 15);
    float* bbw = (float*)(smem + BIASO);
    bbw[tid]       = bp[gi];
    bbw[48 + tid]  = bih0[gi];
    bbw[96 + tid]  = bhh0[gi];
    bbw[144 + tid] = bih1[gi];
    bbw[192 + tid] = bhh1[gi];
  }
  if (tid < 16) {
    const int jg = p*16 + tid;
    float v = (jg < 128) ? bn[jg] : (jg < 192) ? bd[jg-128] : bg[jg-192];
    ((float*)(smem + BIASO))[240 + tid] = v;
  }
  // ---- zero gh0/gh1 scratch slots (3..8) for t=0 semantics ----
  {
    float* S0 = (float*)(smem + SCR);
    const int sidx0 = (tid >> 4)*17 + (tid & 15);
#pragma unroll
    for (int s = 3; s < 9; ++s) S0[s*288 + sidx0] = 0.f;
  }
  // ---- x0 -> HB hi/lo (split f16, XOR-swizzled; validated layout) ----
  {
    const int row = tid >> 4, ch = tid & 15;
    const float* sp = x0in + (size_t)(cl*16 + row)*256 + ch*16;
    const uint32_t base = (uint32_t)(row*512 + ch*32);
    const uint32_t swz  = (uint32_t)((row & 7) << 4);
#pragma unroll
    for (int half = 0; half < 2; ++half) {
      u32x4 vh, vl;
#pragma unroll
      for (int i = 0; i < 4; ++i) {
        float w0 = sp[half*8 + 2*i], w1 = sp[half*8 + 2*i + 1];
        _Float16 h0 = (_Float16)w0, h1 = (_Float16)w1;
        _Float16 l0 = (_Float16)((w0 - (float)h0)*2048.f);
        _Float16 l1 = (_Float16)((w1 - (float)h1)*2048.f);
        vh[i] = (uint32_t)__builtin_bit_cast(uint16_t,h0) | ((uint32_t)__builtin_bit_cast(uint16_t,h1) << 16);
        vl[i] = (uint32_t)__builtin_bit_cast(uint16_t,l0) | ((uint32_t)__builtin_bit_cast(uint16_t,l1) << 16);
      }
      *(u32x4*)(smem + HB_HI + ((base + half*16) ^ swz)) = vh;
      *(u32x4*)(smem + HB_LO + ((base + half*16) ^ swz)) = vl;
    }
  }

  // ---- weight fragments -> registers (round-6 distribution)
  // wv0-2: W' gate wv (hi+lo), Wih1 gate wv (hi+lo) in regs.
  // wv1-3: Whh1 gate wv-1 (hi), Whh0 gate wv-1 (hi) in regs; lo-sets in LDS.
  // wv3: head weights (hi) in LDS.
  half8 wGIh[8], wGIl[8], wI1h[8], wI1l[8], wH1h[8], wH0h[8];
  if (wv < 3) {
#pragma unroll
    for (int kt = 0; kt < 8; ++kt) {
      wGIh[kt] = *(const half8*)(BW + (size_t)(HIU(0,p,wv) + kt*64 + lane)*8);
      wGIl[kt] = *(const half8*)(BW + (size_t)(LOU(0,p,wv) + kt*64 + lane)*8);
      wI1h[kt] = *(const half8*)(BW + (size_t)(HIU(3,p,wv) + kt*64 + lane)*8);
      wI1l[kt] = *(const half8*)(BW + (size_t)(LOU(3,p,wv) + kt*64 + lane)*8);
    }
  }
  const uint32_t h1lo_ofs = WLDS + (uint32_t)(wv-1)*16384u;   // valid for wv>=1
  const uint32_t h0lo_ofs = h1lo_ofs + 8192u;
  if (wv >= 1) {
    const int g = wv - 1;
#pragma unroll
    for (int kt = 0; kt < 8; ++kt) {
      wH1h[kt] = *(const half8*)(BW + (size_t)(HIU(4,p,g) + kt*64 + lane)*8);
      wH0h[kt] = *(const half8*)(BW + (size_t)(HIU(2,p,g) + kt*64 + lane)*8);
      *(u32x4*)(smem + h1lo_ofs + (uint32_t)((kt*64 + lane)*16)) =
          *(const u32x4*)(BW + (size_t)(LOU(4,p,g) + kt*64 + lane)*8);
      *(u32x4*)(smem + h0lo_ofs + (uint32_t)((kt*64 + lane)*16)) =
          *(const u32x4*)(BW + (size_t)(LOU(2,p,g) + kt*64 + lane)*8);
    }
  }
  if (wv == 3) {
#pragma unroll
    for (int kt = 0; kt < 8; ++kt)
      *(u32x4*)(smem + WLDS + 49152u + (uint32_t)((kt*64 + lane)*16)) =
          *(const u32x4*)(BW + (size_t)(HEADU(p) + kt*64 + lane)*8);
  }
  __syncthreads();

  const int arow = lane & 15;
  const uint32_t abase = (uint32_t)(arow*512 + ((lane >> 4) << 4));
  const uint32_t aswz  = (uint32_t)((arow & 7) << 4);

  auto LDA = [&](half8* dst, uint32_t buf) {
#pragma unroll
    for (int kt = 0; kt < 8; ++kt)
      dst[kt] = *(const half8*)(smem + buf + ((abase + (uint32_t)(kt*64)) ^ aswz));
  };
  auto CH = [&](const half8* A, const half8* W, f32x4 acc) -> f32x4 {
#pragma unroll
    for (int kt = 0; kt < 8; ++kt)
      acc = __builtin_amdgcn_mfma_f32_16x16x32_f16(A[kt], W[kt], acc, 0, 0, 0);
    return acc;
  };
  auto CHL = [&](const half8* A, uint32_t wofs, f32x4 acc) -> f32x4 {
#pragma unroll
    for (int kt = 0; kt < 8; ++kt) {
      half8 w = *(const half8*)(smem + wofs + (uint32_t)((kt*64 + lane)*16));
      acc = __builtin_amdgcn_mfma_f32_16x16x32_f16(A[kt], w, acc, 0, 0, 0);
    }
    return acc;
  };
  auto CHG = [&](const half8* A, unsigned ubase, f32x4 acc) -> f32x4 {
#pragma unroll
    for (int kt = 0; kt < 8; ++kt) {
      half8 w = *(const half8*)(BW + (size_t)(ubase + kt*64 + lane)*8);
      acc = __builtin_amdgcn_mfma_f32_16x16x32_f16(A[kt], w, acc, 0, 0, 0);
    }
    return acc;
  };
  auto SCW = [&](int slot, f32x4 a) {   // C layout: col=lane&15, row=(lane>>4)*4+r
    float* sc = (float*)(smem + SCR) + slot*288 + (lane >> 4)*68 + (lane & 15);
    sc[0] = a[0]; sc[17] = a[1]; sc[34] = a[2]; sc[51] = a[3];
  };
  // wv0-only poll: lane l watches flag (cl, block l>>2, wave l&3)
  auto pollw = [&](uint32_t fval) {
    const uint32_t* fp = flags + (uint32_t)((cl << 6) + lane)*16u;
    uint32_t gd = 0;
    for (;;) {
      uint32_t fv;
      asm volatile("global_load_dword %0, %1, off sc0 sc1\n\ts_waitcnt vmcnt(0)"
                   : "=&v"(fv) : "v"(fp) : "memory");
      if (__all((int)(fv >= fval)) || ++gd > 262144u) break;   // bail, don't hang
    }
  };
  auto assemble = [&](uint32_t dhib, uint32_t dlob, const uint32_t* buf) {
    const int row = tid >> 4, ch = tid & 15;
    const uint32_t* bp2 = buf + (uint32_t)(cl*4096 + row*256 + ch*16);
    u32x4 q0, q1, q2, q3;
    asm volatile(
      "global_load_dwordx4 %0, %4, off sc0 sc1\n\t"
      "global_load_dwordx4 %1, %4, off offset:16 sc0 sc1\n\t"
      "global_load_dwordx4 %2, %4, off offset:32 sc0 sc1\n\t"
      "global_load_dwordx4 %3, %4, off offset:48 sc0 sc1\n\t"
      "s_waitcnt vmcnt(0)"
      : "=&v"(q0), "=&v"(q1), "=&v"(q2), "=&v"(q3) : "v"(bp2) : "memory");
    u32x4 hi0, hi1, lo0, lo1;
    hi0[0]=(q0[0]&0xFFFFu)|(q0[1]<<16); lo0[0]=(q0[0]>>16)|(q0[1]&0xFFFF0000u);
    hi0[1]=(q0[2]&0xFFFFu)|(q0[3]<<16); lo0[1]=(q0[2]>>16)|(q0[3]&0xFFFF0000u);
    hi0[2]=(q1[0]&0xFFFFu)|(q1[1]<<16); lo0[2]=(q1[0]>>16)|(q1[1]&0xFFFF0000u);
    hi0[3]=(q1[2]&0xFFFFu)|(q1[3]<<16); lo0[3]=(q1[2]>>16)|(q1[3]&0xFFFF0000u);
    hi1[0]=(q2[0]&0xFFFFu)|(q2[1]<<16); lo1[0]=(q2[0]>>16)|(q2[1]&0xFFFF0000u);
    hi1[1]=(q2[2]&0xFFFFu)|(q2[3]<<16); lo1[1]=(q2[2]>>16)|(q2[3]&0xFFFF0000u);
    hi1[2]=(q3[0]&0xFFFFu)|(q3[1]<<16); lo1[2]=(q3[0]>>16)|(q3[1]&0xFFFF0000u);
    hi1[3]=(q3[2]&0xFFFFu)|(q3[3]<<16); lo1[3]=(q3[2]>>16)|(q3[3]&0xFFFF0000u);
    const uint32_t base = (uint32_t)(row*512 + ch*32);
    const uint32_t swz  = (uint32_t)((row & 7) << 4);
    *(u32x4*)(smem + dhib + (base ^ swz))        = hi0;
    *(u32x4*)(smem + dhib + ((base + 16) ^ swz)) = hi1;
    *(u32x4*)(smem + dlob + (base ^ swz))        = lo0;
    *(u32x4*)(smem + dlob + ((base + 16) ^ swz)) = lo1;
  };

  float h0keep = 0.f, h1keep = 0.f;
  const float* bb = (const float*)(smem + BIASO);
  const float* S  = (const float*)(smem + SCR);
  const float INV = 1.0f/2048.0f;
  const f32x4 Z = {0.f, 0.f, 0.f, 0.f};
  const int ef   = tid & 15;
  const int sidx = (tid >> 4)*17 + ef;
  const uint32_t pidx = (uint32_t)(cl*4096 + (tid >> 4)*256 + p*16 + ef);
  uint32_t* myflag = flags + (uint32_t)((cl << 6) + (p << 2) + wv)*16u;

  half8 a1h[8], a1l[8], a0h[8], a0l[8];

  auto head_out = [&](int tstep) {   // uses a1h (= h1n(tstep) from HB)
    f32x4 hc = CHL(a1h, WLDS + 49152u, Z);
    const int col = lane & 15;
    const int jgl = p*16 + col;
    const float bo = bb[240 + col];
#pragma unroll
    for (int r = 0; r < 4; ++r) {
      const int brow = cl*16 + (lane >> 4)*4 + r;
      const float v = hc[r] + bo;
      size_t o;
      if (jgl < 128)      o = ((size_t)brow*512 + (size_t)tstep)*128 + (size_t)jgl;
      else if (jgl < 192) o = 8388608u  + ((size_t)brow*512 + (size_t)tstep)*64 + (size_t)(jgl - 128);
      else                o = 12582912u + ((size_t)brow*512 + (size_t)tstep)*64 + (size_t)(jgl - 192);
      out[o] = v;
    }
  };

#pragma unroll 1
  for (int t = 0; t < 512; ++t) {
    LDA(a1h, HB_HI); LDA(a1l, HB_LO);   // h1(t-1) / x0

    // ---- phase A: gi0 (wv0-2); head(t-1) on wv3
    if (t == 0) {
      if (wv < 3) {
        f32x4 m  = CHG(a1h, HIU(1,p,wv), Z);
        f32x4 c1 = CHG(a1l, HIU(1,p,wv), Z);
        f32x4 c2 = CHG(a1h, LOU(1,p,wv), Z);
        SCW(wv, m + (c1 + c2)*INV);
      }
    } else {
      if (wv < 3) {
        f32x4 m  = CH(a1h, wGIh, Z);
        f32x4 c1 = CH(a1l, wGIh, Z);
        f32x4 c2 = CH(a1h, wGIl, Z);
        SCW(wv, m + (c1 + c2)*INV);
      } else {
        head_out(t - 1);
      }
    }
    __syncthreads();                                  // B1

    // ---- L0 elementwise (slots 0-2 gi0, 3-5 gh0) -> publish h0n
    {
      const float* bA = bb + (t == 0 ? 48 : 0);
      float ir = S[sidx]        + bA[ef];
      float iz = S[288 + sidx]  + bA[16 + ef];
      float ix = S[576 + sidx]  + bA[32 + ef];
      float hr = S[864 + sidx]  + bb[96 + ef];
      float hz = S[1152 + sidx] + bb[112 + ef];
      float hn = S[1440 + sidx] + bb[128 + ef];
      float rg = sigmoidf_(ir + hr);
      float zg = sigmoidf_(iz + hz);
      float ng = tanhf(ix + rg*hn);
      float h  = (1.f - zg)*ng + zg*h0keep;
      h0keep = h;
      _Float16 hh = (_Float16)h;
      _Float16 hl = (_Float16)((h - (float)hh)*2048.f);
      st_cc_d(pub0 + pidx, (uint32_t)__builtin_bit_cast(uint16_t, hh)
                         | ((uint32_t)__builtin_bit_cast(uint16_t, hl) << 16));
    }
    // ---- exchange 1: reg-chains hide drain; c2+SCW hide flag propagation
    {
      f32x4 m1 = Z, c1a = Z;
      if (t > 0 && wv >= 1) {
        m1  = CH(a1h, wH1h, Z);      // gh1(t) = Whh1 . h1(t-1), reg-only
        c1a = CH(a1l, wH1h, Z);
      }
      __builtin_amdgcn_sched_barrier(0);              // pin MFMAs before drain
      asm volatile("s_waitcnt vmcnt(0)" ::: "memory"); // per-wave pub drain
      if (lane == 0) st_cc_d(myflag, (uint32_t)(t*2 + 1));
      if (t > 0 && wv >= 1) {
        f32x4 c2 = CHL(a1h, h1lo_ofs, Z);
        SCW(5 + wv, m1 + (c1a + c2)*INV);             // slots 6,7,8
      }
      if (wv == 0) pollw((uint32_t)(t*2 + 1));
    }
    __syncthreads();                                  // Bex1a (poll + SCW done)
    assemble(HA_HI, HA_LO, pub0);                     // full h0n(t)
    __syncthreads();                                  // Bex1b (HA ready)

    // ---- phase B: gi1 (wv0-2) -> slots 0-2
    LDA(a0h, HA_HI); LDA(a0l, HA_LO);
    if (wv < 3) {
      f32x4 m  = CH(a0h, wI1h, Z);
      f32x4 c1 = CH(a0l, wI1h, Z);
      f32x4 c2 = CH(a0h, wI1l, Z);
      SCW(wv, m + (c1 + c2)*INV);
    }
    __syncthreads();                                  // B2

    // ---- L1 elementwise (slots 0-2 gi1, 6-8 gh1) -> publish h1n
    {
      float ir = S[sidx]        + bb[144 + ef];
      float iz = S[288 + sidx]  + bb[160 + ef];
      float ix = S[576 + sidx]  + bb[176 + ef];
      float hr = S[1728 + sidx] + bb[192 + ef];
      float hz = S[2016 + sidx] + bb[208 + ef];
      float hn = S[2304 + sidx] + bb[224 + ef];
      float rg = sigmoidf_(ir + hr);
      float zg = sigmoidf_(iz + hz);
      float ng = tanhf(ix + rg*hn);
      float h  = (1.f - zg)*ng + zg*h1keep;
      h1keep = h;
      _Float16 hh = (_Float16)h;
      _Float16 hl = (_Float16)((h - (float)hh)*2048.f);
      st_cc_d(pub1 + pidx, (uint32_t)__builtin_bit_cast(uint16_t, hh)
                         | ((uint32_t)__builtin_bit_cast(uint16_t, hl) << 16));
    }
    // ---- exchange 2: gh0(t+1) split the same way
    {
      f32x4 m2 = Z, c1b = Z;
      if (wv >= 1) {
        m2  = CH(a0h, wH0h, Z);      // gh0(t+1) = Whh0 . h0n(t), reg-only
        c1b = CH(a0l, wH0h, Z);
      }
      __builtin_amdgcn_sched_barrier(0);
      asm volatile("s_waitcnt vmcnt(0)" ::: "memory");
      if (lane == 0) st_cc_d(myflag, (uint32_t)(t*2 + 2));
      if (wv >= 1) {
        f32x4 c2 = CHL(a0h, h0lo_ofs, Z);
        SCW(2 + wv, m2 + (c1b + c2)*INV);             // slots 3,4,5
      }
      if (wv == 0) pollw((uint32_t)(t*2 + 2));
    }
    __syncthreads();                                  // Bex2a
    assemble(HB_HI, HB_LO, pub1);                     // full h1n(t)
    __syncthreads();                                  // Bex2b
  }

  // epilogue: head for t=511
  if (wv == 3) {
    LDA(a1h, HB_HI);
    head_out(511);
  }
}

// ---------------------------------------------------------------------------
extern "C" void kernel_launch(void* const* d_in, const int* in_sizes, int n_in,
                              void* d_out, int out_size, void* d_ws, size_t ws_size,
                              hipStream_t stream) {
  (void)in_sizes; (void)n_in; (void)out_size;
  const float* x0   = (const float*)d_in[2];
  const float* Wih0 = (const float*)d_in[3];
  const float* Whh0 = (const float*)d_in[4];
  const float* bih0 = (const float*)d_in[5];
  const float* bhh0 = (const float*)d_in[6];
  const float* Wih1 = (const float*)d_in[7];
  const float* Whh1 = (const float*)d_in[8];
  const float* bih1 = (const float*)d_in[9];
  const float* bhh1 = (const float*)d_in[10];
  const float* Wn   = (const float*)d_in[11];
  const float* bn   = (const float*)d_in[12];
  const float* Wd   = (const float*)d_in[13];
  const float* bd   = (const float*)d_in[14];
  const float* Wg   = (const float*)d_in[15];
  const float* bg   = (const float*)d_in[16];

  if (ws_size < WS_NEEDED) return;  // fail loudly (poisoned output) rather than corrupt

  char* ws = (char*)d_ws;
  uint32_t* flags = (uint32_t*)(ws + FLAGS_OFF);
  uint32_t* pub0  = (uint32_t*)(ws + PUB0_OFF);
  uint32_t* pub1  = (uint32_t*)(ws + PUB1_OFF);
  float*    bp    = (float*)(ws + BP_OFF);
  uint16_t* BW    = (uint16_t*)(ws + BLOB_OFF);

  gru_init1<<<768, 256, 0, stream>>>(Wih0, Wn, Wd, Wg, bn, bd, bg, bih0, BW, bp);
  gru_init2<<<992, 256, 0, stream>>>(Wih0, Whh0, Wih1, Whh1, Wn, Wd, Wg, flags, BW);
  gru_main <<<128, 256, LDS_TOTAL, stream>>>(x0, bih0, bhh0, bih1, bhh1, bn, bd, bg, bp,
                                             BW, flags, pub0, pub1, (float*)d_out);
}

// Round 11
// 2785.798 us; speedup vs baseline: 1.1143x; 1.1143x over previous
//
#include <hip/hip_runtime.h>
#include <stdint.h>

// ============================================================================
// 2-layer GRU decoder, B=128, T=512, H=256, heads 128/64/64 (concat=256).
// Persistent latency design + SPLIT-F16 precision (effectively fp32 matmuls):
//   A*W ~= Ah*Wh + (Al_s*Wh + Ah*Wl_s)/2048, lo-parts pre-scaled by 2^11.
// Round-11 = round-6 (2739us, best) + ONE change: the reg-only gh chains
//   (m, c1) issue BETWEEN publish and vmcnt(0), pinned by sched_barrier(0),
//   hiding the store-ack drain under MFMA on waves 1-3. Everything else --
//   per-BLOCK flag stored by tid0 after a block barrier, wv0-only 16-line
//   poll, c2+SCW after the flag (hides flag propagation), 8 barriers/step,
//   sc0 sc1 system scope -- is byte-identical to round 6.
//   (r8/r10 lesson: poll footprint 16 lines/block is the optimum; r7 lesson:
//    flag must follow the drain; r5 lesson: sc0-only is CU-scope.)
// ============================================================================

typedef __attribute__((ext_vector_type(8))) _Float16 half8;
typedef __attribute__((ext_vector_type(4))) float f32x4;
typedef __attribute__((ext_vector_type(4))) unsigned int u32x4;

// blob fragment-unit (16B) section bases: b=0 W', 1 Wih0, 2 Whh0, 3 Wih1, 4 Whh1
#define HIU(b,p,g)  ((unsigned)((b)*24576u + ((p)*3u+(g))*512u))
#define LOU(b,p,g)  ((unsigned)(122880u + (b)*24576u + ((p)*3u+(g))*512u))
#define HEADU(p)    ((unsigned)(245760u + (p)*512u))
#define NUNITS      253952u

// workspace offsets (bytes)
#define FLAGS_OFF 0u            // flag of block (cl,p) at u32 index (cl*16+p)*16
#define PUB0_OFF  16384u        // 32768 u32 (hi|lo<<16)
#define PUB1_OFF  147456u
#define BP_OFF    278528u
#define BLOB_OFF  281600u
#define WS_NEEDED (BLOB_OFF + NUNITS*16u)

// LDS offsets (bytes)  — round-6 layout
#define HA_HI 0u
#define HA_LO 8192u
#define HB_HI 16384u
#define HB_LO 24576u
#define SCR   32768u        // 9 slots * 288 fp32 (17-stride pad) = 10368B
#define BIASO 43136u        // 256 floats
#define WLDS  44160u        // wv1..3: h1lo+h0lo (16KB each); head hi at +49152
#define LDS_TOTAL (44160u + 57344u)   // 101504 B

__device__ __forceinline__ uint16_t f2h_bits(float x) {
  _Float16 h = (_Float16)x;
  return __builtin_bit_cast(uint16_t, h);
}
__device__ __forceinline__ float sigmoidf_(float x) { return 1.f / (1.f + __expf(-x)); }

// system-scope (LLC) coherent store — validated rounds 3/6
__device__ __forceinline__ void st_cc_d(uint32_t* p, uint32_t v) {
  asm volatile("global_store_dword %0, %1, off sc0 sc1" :: "v"(p), "v"(v) : "memory");
}

// ---------------------------------------------------------------------------
// init1: W' = Wih0 @ Wcat written DIRECTLY as split-f16 blob (b=0 sections);
//        b' = bih0 + Wih0 . bcat -> bp.   (validated rounds 4/6)
// ---------------------------------------------------------------------------
__global__ void gru_init1(const float* __restrict__ Wih0, const float* __restrict__ Wn,
                          const float* __restrict__ Wd, const float* __restrict__ Wg,
                          const float* __restrict__ bn, const float* __restrict__ bd,
                          const float* __restrict__ bg, const float* __restrict__ bih0,
                          uint16_t* __restrict__ BW, float* __restrict__ bp)
{
  const int i = blockIdx.x;   // 0..767  (gate-major row of W')
  const int j = threadIdx.x;  // 0..255  (column)
  float acc = 0.f;
  for (int k = 0; k < 256; ++k) {
    float w = Wih0[i*256 + k];
    float c = (k < 128) ? Wn[k*256 + j] : (k < 192) ? Wd[(k-128)*256 + j] : Wg[(k-192)*256 + j];
    acc += w * c;
  }
  const uint32_t g = (uint32_t)i >> 8, p = ((uint32_t)i & 255u) >> 4, r = (uint32_t)i & 15u;
  const uint32_t kt = (uint32_t)j >> 5, c4 = ((uint32_t)j >> 3) & 3u, e = (uint32_t)j & 7u;
  const uint32_t base = ((p*3u + g)*512u + kt*64u + c4*16u + r)*8u + e;
  _Float16 hi = (_Float16)acc;
  BW[base] = __builtin_bit_cast(uint16_t, hi);
  BW[122880u*8u + base] = f2h_bits((acc - (float)hi) * 2048.f);
  if (j == 0) {
    float bb = bih0[i];
    for (int k = 0; k < 256; ++k) {
      float bc = (k < 128) ? bn[k] : (k < 192) ? bd[k-128] : bg[k-192];
      bb += Wih0[i*256 + k] * bc;
    }
    bp[i] = bb;
  }
}

// ---------------------------------------------------------------------------
// init2: split-f16 blobs for b=1..4 + head; b=0-range threads zero the flags
// (system-scope stores; flags monotonic within a launch -> replay-safe).
// ---------------------------------------------------------------------------
__global__ void gru_init2(const float* __restrict__ Wih0, const float* __restrict__ Whh0,
                          const float* __restrict__ Wih1, const float* __restrict__ Whh1,
                          const float* __restrict__ Wn, const float* __restrict__ Wd,
                          const float* __restrict__ Wg,
                          uint32_t* __restrict__ flags, uint16_t* __restrict__ BW)
{
  const uint32_t u = blockIdx.x*256u + threadIdx.x;   // 0..253951
  const bool isB0 = (u < 24576u) || (u >= 122880u && u < 147456u);
  if (isB0) {
    const uint32_t zi = (u < 24576u) ? u : (u - 122880u + 24576u);  // 0..49151
    if (zi < 2048u) st_cc_d(flags + zi, 0u);
    return;
  }
  bool lo = false;
  const float* s;
  if (u < 245760u) {
    uint32_t v = u;
    if (v >= 122880u) { v -= 122880u; lo = true; }
    uint32_t b = v/24576u, rem = v%24576u;          // b in 1..4 here
    uint32_t p = rem/1536u, r2 = rem%1536u;
    uint32_t g = r2/512u,  r3 = r2%512u;
    uint32_t kt = r3>>6,   l = r3&63u;
    const float* W = (b==1)?Wih0:(b==2)?Whh0:(b==3)?Wih1:Whh1;
    s = W + (size_t)(g*256u + p*16u + (l&15u))*256u + kt*32u + (l>>4)*8u;
  } else {
    uint32_t rem = u - 245760u;
    uint32_t p = rem/512u, r3 = rem%512u;
    uint32_t kt = r3>>6,   l = r3&63u;
    uint32_t row = p*16u + (l&15u), k0 = kt*32u + (l>>4)*8u;
    s = (row < 128u) ? (Wn + (size_t)row*256u + k0)
      : (row < 192u) ? (Wd + (size_t)(row-128u)*256u + k0)
      :                (Wg + (size_t)(row-192u)*256u + k0);
  }
  u32x4 vv;
#pragma unroll
  for (int i = 0; i < 4; ++i) {
    float w0 = s[2*i], w1 = s[2*i+1];
    uint16_t b0, b1;
    if (!lo) { b0 = f2h_bits(w0); b1 = f2h_bits(w1); }
    else {
      float r0 = w0 - (float)((_Float16)w0);
      float r1 = w1 - (float)((_Float16)w1);
      b0 = f2h_bits(r0 * 2048.f); b1 = f2h_bits(r1 * 2048.f);
    }
    vv[i] = (uint32_t)b0 | ((uint32_t)b1 << 16);
  }
  *(u32x4*)(BW + (size_t)u * 8u) = vv;
}

// ---------------------------------------------------------------------------
// main persistent kernel: 128 blocks x 256 threads, 512 steps.
// ---------------------------------------------------------------------------
__launch_bounds__(256, 1)
__global__ void gru_main(const float* __restrict__ x0in,
                         const float* __restrict__ bih0, const float* __restrict__ bhh0,
                         const float* __restrict__ bih1, const float* __restrict__ bhh1,
                         const float* __restrict__ bn, const float* __restrict__ bd,
                         const float* __restrict__ bg, const float* __restrict__ bp,
                         const uint16_t* __restrict__ BW,
                         uint32_t* __restrict__ flags,
                         uint32_t* __restrict__ pub0, uint32_t* __restrict__ pub1,
                         float* __restrict__ out)
{
  extern __shared__ char smem[];
  const int tid  = threadIdx.x;
  const int lane = tid & 63;
  const int wv   = tid >> 6;
  const int cl   = blockIdx.x & 7;
  const int p    = blockIdx.x >> 3;

  // ---- biases -> LDS: [0)b' [48)bih0 [96)bhh0 [144)bih1 [192)bhh1 [240)bhead
  if (tid < 48) {
    const int gi = (tid >> 4)*256 + p*16 + (tid & 15);
    float* bbw = (float*)(smem + BIASO);
    bbw[tid]       = bp[gi];
    bbw[48 + tid]  = bih0[gi];
    bbw[96 + tid]  = bhh0[gi];
    bbw[144 + tid] = bih1[gi];
    bbw[192 + tid] = bhh1[gi];
  }
  if (tid < 16) {
    const int jg = p*16 + tid;
    float v = (jg < 128) ? bn[jg] : (jg < 192) ? bd[jg-128] : bg[jg-192];
    ((float*)(smem + BIASO))[240 + tid] = v;
  }
  // ---- zero gh0/gh1 scratch slots (3..8) for t=0 semantics ----
  {
    float* S0 = (float*)(smem + SCR);
    const int sidx0 = (tid >> 4)*17 + (tid & 15);
#pragma unroll
    for (int s = 3; s < 9; ++s) S0[s*288 + sidx0] = 0.f;
  }
  // ---- x0 -> HB hi/lo (split f16, XOR-swizzled; validated layout) ----
  {
    const int row = tid >> 4, ch = tid & 15;
    const float* sp = x0in + (size_t)(cl*16 + row)*256 + ch*16;
    const uint32_t base = (uint32_t)(row*512 + ch*32);
    const uint32_t swz  = (uint32_t)((row & 7) << 4);
#pragma unroll
    for (int half = 0; half < 2; ++half) {
      u32x4 vh, vl;
#pragma unroll
      for (int i = 0; i < 4; ++i) {
        float w0 = sp[half*8 + 2*i], w1 = sp[half*8 + 2*i + 1];
        _Float16 h0 = (_Float16)w0, h1 = (_Float16)w1;
        _Float16 l0 = (_Float16)((w0 - (float)h0)*2048.f);
        _Float16 l1 = (_Float16)((w1 - (float)h1)*2048.f);
        vh[i] = (uint32_t)__builtin_bit_cast(uint16_t,h0) | ((uint32_t)__builtin_bit_cast(uint16_t,h1) << 16);
        vl[i] = (uint32_t)__builtin_bit_cast(uint16_t,l0) | ((uint32_t)__builtin_bit_cast(uint16_t,l1) << 16);
      }
      *(u32x4*)(smem + HB_HI + ((base + half*16) ^ swz)) = vh;
      *(u32x4*)(smem + HB_LO + ((base + half*16) ^ swz)) = vl;
    }
  }

  // ---- weight fragments -> registers (round-6 distribution)
  // wv0-2: W' gate wv (hi+lo), Wih1 gate wv (hi+lo) in regs.
  // wv1-3: Whh1 gate wv-1 (hi), Whh0 gate wv-1 (hi) in regs; lo-sets in LDS.
  // wv3: head weights (hi) in LDS.
  half8 wGIh[8], wGIl[8], wI1h[8], wI1l[8], wH1h[8], wH0h[8];
  if (wv < 3) {
#pragma unroll
    for (int kt = 0; kt < 8; ++kt) {
      wGIh[kt] = *(const half8*)(BW + (size_t)(HIU(0,p,wv) + kt*64 + lane)*8);
      wGIl[kt] = *(const half8*)(BW + (size_t)(LOU(0,p,wv) + kt*64 + lane)*8);
      wI1h[kt] = *(const half8*)(BW + (size_t)(HIU(3,p,wv) + kt*64 + lane)*8);
      wI1l[kt] = *(const half8*)(BW + (size_t)(LOU(3,p,wv) + kt*64 + lane)*8);
    }
  }
  const uint32_t h1lo_ofs = WLDS + (uint32_t)(wv-1)*16384u;   // valid for wv>=1
  const uint32_t h0lo_ofs = h1lo_ofs + 8192u;
  if (wv >= 1) {
    const int g = wv - 1;
#pragma unroll
    for (int kt = 0; kt < 8; ++kt) {
      wH1h[kt] = *(const half8*)(BW + (size_t)(HIU(4,p,g) + kt*64 + lane)*8);
      wH0h[kt] = *(const half8*)(BW + (size_t)(HIU(2,p,g) + kt*64 + lane)*8);
      *(u32x4*)(smem + h1lo_ofs + (uint32_t)((kt*64 + lane)*16)) =
          *(const u32x4*)(BW + (size_t)(LOU(4,p,g) + kt*64 + lane)*8);
      *(u32x4*)(smem + h0lo_ofs + (uint32_t)((kt*64 + lane)*16)) =
          *(const u32x4*)(BW + (size_t)(LOU(2,p,g) + kt*64 + lane)*8);
    }
  }
  if (wv == 3) {
#pragma unroll
    for (int kt = 0; kt < 8; ++kt)
      *(u32x4*)(smem + WLDS + 49152u + (uint32_t)((kt*64 + lane)*16)) =
          *(const u32x4*)(BW + (size_t)(HEADU(p) + kt*64 + lane)*8);
  }
  __syncthreads();

  const int arow = lane & 15;
  const uint32_t abase = (uint32_t)(arow*512 + ((lane >> 4) << 4));
  const uint32_t aswz  = (uint32_t)((arow & 7) << 4);

  auto LDA = [&](half8* dst, uint32_t buf) {
#pragma unroll
    for (int kt = 0; kt < 8; ++kt)
      dst[kt] = *(const half8*)(smem + buf + ((abase + (uint32_t)(kt*64)) ^ aswz));
  };
  auto CH = [&](const half8* A, const half8* W, f32x4 acc) -> f32x4 {
#pragma unroll
    for (int kt = 0; kt < 8; ++kt)
      acc = __builtin_amdgcn_mfma_f32_16x16x32_f16(A[kt], W[kt], acc, 0, 0, 0);
    return acc;
  };
  auto CHL = [&](const half8* A, uint32_t wofs, f32x4 acc) -> f32x4 {
#pragma unroll
    for (int kt = 0; kt < 8; ++kt) {
      half8 w = *(const half8*)(smem + wofs + (uint32_t)((kt*64 + lane)*16));
      acc = __builtin_amdgcn_mfma_f32_16x16x32_f16(A[kt], w, acc, 0, 0, 0);
    }
    return acc;
  };
  auto CHG = [&](const half8* A, unsigned ubase, f32x4 acc) -> f32x4 {
#pragma unroll
    for (int kt = 0; kt < 8; ++kt) {
      half8 w = *(const half8*)(BW + (size_t)(ubase + kt*64 + lane)*8);
      acc = __builtin_amdgcn_mfma_f32_16x16x32_f16(A[kt], w, acc, 0, 0, 0);
    }
    return acc;
  };
  auto SCW = [&](int slot, f32x4 a) {   // C layout: col=lane&15, row=(lane>>4)*4+r
    float* sc = (float*)(smem + SCR) + slot*288 + (lane >> 4)*68 + (lane & 15);
    sc[0] = a[0]; sc[17] = a[1]; sc[34] = a[2]; sc[51] = a[3];
  };
  auto pollf = [&](uint32_t fval) {   // wave-0 only; 16 flags, system scope
    const uint32_t* fp = flags + (cl*16 + (lane & 15))*16;
    uint32_t gd = 0;
    for (;;) {
      uint32_t fv;
      asm volatile("global_load_dword %0, %1, off sc0 sc1\n\ts_waitcnt vmcnt(0)"
                   : "=&v"(fv) : "v"(fp) : "memory");
      if (__all((int)(fv >= fval)) || ++gd > 65536u) break;   // bail, don't hang
    }
  };
  auto assemble = [&](uint32_t dhib, uint32_t dlob, const uint32_t* buf) {
    const int row = tid >> 4, ch = tid & 15;
    const uint32_t* bp2 = buf + (uint32_t)(cl*4096 + row*256 + ch*16);
    u32x4 q0, q1, q2, q3;
    asm volatile(
      "global_load_dwordx4 %0, %4, off sc0 sc1\n\t"
      "global_load_dwordx4 %1, %4, off offset:16 sc0 sc1\n\t"
      "global_load_dwordx4 %2, %4, off offset:32 sc0 sc1\n\t"
      "global_load_dwordx4 %3, %4, off offset:48 sc0 sc1\n\t"
      "s_waitcnt vmcnt(0)"
      : "=&v"(q0), "=&v"(q1), "=&v"(q2), "=&v"(q3) : "v"(bp2) : "memory");
    u32x4 hi0, hi1, lo0, lo1;
    hi0[0]=(q0[0]&0xFFFFu)|(q0[1]<<16); lo0[0]=(q0[0]>>16)|(q0[1]&0xFFFF0000u);
    hi0[1]=(q0[2]&0xFFFFu)|(q0[3]<<16); lo0[1]=(q0[2]>>16)|(q0[3]&0xFFFF0000u);
    hi0[2]=(q1[0]&0xFFFFu)|(q1[1]<<16); lo0[2]=(q1[0]>>16)|(q1[1]&0xFFFF0000u);
    hi0[3]=(q1[2]&0xFFFFu)|(q1[3]<<16); lo0[3]=(q1[2]>>16)|(q1[3]&0xFFFF0000u);
    hi1[0]=(q2[0]&0xFFFFu)|(q2[1]<<16); lo1[0]=(q2[0]>>16)|(q2[1]&0xFFFF0000u);
    hi1[1]=(q2[2]&0xFFFFu)|(q2[3]<<16); lo1[1]=(q2[2]>>16)|(q2[3]&0xFFFF0000u);
    hi1[2]=(q3[0]&0xFFFFu)|(q3[1]<<16); lo1[2]=(q3[0]>>16)|(q3[1]&0xFFFF0000u);
    hi1[3]=(q3[2]&0xFFFFu)|(q3[3]<<16); lo1[3]=(q3[2]>>16)|(q3[3]&0xFFFF0000u);
    const uint32_t base = (uint32_t)(row*512 + ch*32);
    const uint32_t swz  = (uint32_t)((row & 7) << 4);
    *(u32x4*)(smem + dhib + (base ^ swz))        = hi0;
    *(u32x4*)(smem + dhib + ((base + 16) ^ swz)) = hi1;
    *(u32x4*)(smem + dlob + (base ^ swz))        = lo0;
    *(u32x4*)(smem + dlob + ((base + 16) ^ swz)) = lo1;
  };

  float h0keep = 0.f, h1keep = 0.f;
  const float* bb = (const float*)(smem + BIASO);
  const float* S  = (const float*)(smem + SCR);
  const float INV = 1.0f/2048.0f;
  const f32x4 Z = {0.f, 0.f, 0.f, 0.f};
  const int ef   = tid & 15;
  const int sidx = (tid >> 4)*17 + ef;
  const uint32_t pidx = (uint32_t)(cl*4096 + (tid >> 4)*256 + p*16 + ef);
  uint32_t* myflag = flags + (cl*16 + p)*16;

  half8 a1h[8], a1l[8], a0h[8], a0l[8];

  auto head_out = [&](int tstep) {   // uses a1h (= h1n(tstep) from HB)
    f32x4 hc = CHL(a1h, WLDS + 49152u, Z);
    const int col = lane & 15;
    const int jgl = p*16 + col;
    const float bo = bb[240 + col];
#pragma unroll
    for (int r = 0; r < 4; ++r) {
      const int brow = cl*16 + (lane >> 4)*4 + r;
      const float v = hc[r] + bo;
      size_t o;
      if (jgl < 128)      o = ((size_t)brow*512 + (size_t)tstep)*128 + (size_t)jgl;
      else if (jgl < 192) o = 8388608u  + ((size_t)brow*512 + (size_t)tstep)*64 + (size_t)(jgl - 128);
      else                o = 12582912u + ((size_t)brow*512 + (size_t)tstep)*64 + (size_t)(jgl - 192);
      out[o] = v;
    }
  };

#pragma unroll 1
  for (int t = 0; t < 512; ++t) {
    LDA(a1h, HB_HI); LDA(a1l, HB_LO);   // h1(t-1) / x0

    // ---- phase A: gi0 (wv0-2); head(t-1) on wv3
    if (t == 0) {
      if (wv < 3) {
        f32x4 m  = CHG(a1h, HIU(1,p,wv), Z);
        f32x4 c1 = CHG(a1l, HIU(1,p,wv), Z);
        f32x4 c2 = CHG(a1h, LOU(1,p,wv), Z);
        SCW(wv, m + (c1 + c2)*INV);
      }
    } else {
      if (wv < 3) {
        f32x4 m  = CH(a1h, wGIh, Z);
        f32x4 c1 = CH(a1l, wGIh, Z);
        f32x4 c2 = CH(a1h, wGIl, Z);
        SCW(wv, m + (c1 + c2)*INV);
      } else {
        head_out(t - 1);
      }
    }
    __syncthreads();

    // ---- elementwise layer 0 -> publish h0n  (gh0(t) from slots 3-5)
    {
      const float* bA = bb + (t == 0 ? 48 : 0);
      float ir = S[sidx]        + bA[ef];
      float iz = S[288 + sidx]  + bA[16 + ef];
      float ix = S[576 + sidx]  + bA[32 + ef];
      float hr = S[864 + sidx]  + bb[96 + ef];
      float hz = S[1152 + sidx] + bb[112 + ef];
      float hn = S[1440 + sidx] + bb[128 + ef];
      float rg = sigmoidf_(ir + hr);
      float zg = sigmoidf_(iz + hz);
      float ng = tanhf(ix + rg*hn);
      float h  = (1.f - zg)*ng + zg*h0keep;
      h0keep = h;
      _Float16 hh = (_Float16)h;
      _Float16 hl = (_Float16)((h - (float)hh)*2048.f);
      st_cc_d(pub0 + pidx, (uint32_t)__builtin_bit_cast(uint16_t, hh)
                         | ((uint32_t)__builtin_bit_cast(uint16_t, hl) << 16));
    }
    // ---- exchange 1 (round-6 protocol; ONLY change: m,c1 issued pre-drain)
    {
      f32x4 m1 = Z, c1a = Z;
      if (t > 0 && wv >= 1) {
        m1  = CH(a1h, wH1h, Z);      // gh1(t) = Whh1 . h1(t-1), reg-only
        c1a = CH(a1l, wH1h, Z);
      }
      __builtin_amdgcn_sched_barrier(0);               // pin MFMAs before drain
      asm volatile("s_waitcnt vmcnt(0)" ::: "memory"); // pub drain (now hidden)
      __syncthreads();
      if (tid == 0) st_cc_d(myflag, (uint32_t)(t*2 + 1));
      if (t > 0 && wv >= 1) {
        f32x4 c2 = CHL(a1h, h1lo_ofs, Z);
        SCW(5 + wv, m1 + (c1a + c2)*INV);              // slots 6,7,8 (r,z,n)
      }
      if (wv == 0) pollf((uint32_t)(t*2 + 1));
    }
    __syncthreads();
    assemble(HA_HI, HA_LO, pub0);   // full h0n(t)
    __syncthreads();

    // ---- phase B: gi1 (wv0-2)
    LDA(a0h, HA_HI); LDA(a0l, HA_LO);
    if (wv < 3) {
      f32x4 m  = CH(a0h, wI1h, Z);
      f32x4 c1 = CH(a0l, wI1h, Z);
      f32x4 c2 = CH(a0h, wI1l, Z);
      SCW(wv, m + (c1 + c2)*INV);
    }
    __syncthreads();

    // ---- elementwise layer 1 -> publish h1n  (gh1(t) from slots 6-8)
    {
      float ir = S[sidx]        + bb[144 + ef];
      float iz = S[288 + sidx]  + bb[160 + ef];
      float ix = S[576 + sidx]  + bb[176 + ef];
      float hr = S[1728 + sidx] + bb[192 + ef];
      float hz = S[2016 + sidx] + bb[208 + ef];
      float hn = S[2304 + sidx] + bb[224 + ef];
      float rg = sigmoidf_(ir + hr);
      float zg = sigmoidf_(iz + hz);
      float ng = tanhf(ix + rg*hn);
      float h  = (1.f - zg)*ng + zg*h1keep;
      h1keep = h;
      _Float16 hh = (_Float16)h;
      _Float16 hl = (_Float16)((h - (float)hh)*2048.f);
      st_cc_d(pub1 + pidx, (uint32_t)__builtin_bit_cast(uint16_t, hh)
                         | ((uint32_t)__builtin_bit_cast(uint16_t, hl) << 16));
    }
    // ---- exchange 2 (same single change)
    {
      f32x4 m2 = Z, c1b = Z;
      if (wv >= 1) {
        m2  = CH(a0h, wH0h, Z);      // gh0(t+1) = Whh0 . h0n(t), reg-only
        c1b = CH(a0l, wH0h, Z);
      }
      __builtin_amdgcn_sched_barrier(0);
      asm volatile("s_waitcnt vmcnt(0)" ::: "memory");
      __syncthreads();
      if (tid == 0) st_cc_d(myflag, (uint32_t)(t*2 + 2));
      if (wv >= 1) {
        f32x4 c2 = CHL(a0h, h0lo_ofs, Z);
        SCW(2 + wv, m2 + (c1b + c2)*INV);              // slots 3,4,5 (r,z,n)
      }
      if (wv == 0) pollf((uint32_t)(t*2 + 2));
    }
    __syncthreads();
    assemble(HB_HI, HB_LO, pub1);   // full h1n(t)
    __syncthreads();
  }

  // epilogue: head for t=511
  if (wv == 3) {
    LDA(a1h, HB_HI);
    head_out(511);
  }
}

// ---------------------------------------------------------------------------
extern "C" void kernel_launch(void* const* d_in, const int* in_sizes, int n_in,
                              void* d_out, int out_size, void* d_ws, size_t ws_size,
                              hipStream_t stream) {
  (void)in_sizes; (void)n_in; (void)out_size;
  const float* x0   = (const float*)d_in[2];
  const float* Wih0 = (const float*)d_in[3];
  const float* Whh0 = (const float*)d_in[4];
  const float* bih0 = (const float*)d_in[5];
  const float* bhh0 = (const float*)d_in[6];
  const float* Wih1 = (const float*)d_in[7];
  const float* Whh1 = (const float*)d_in[8];
  const float* bih1 = (const float*)d_in[9];
  const float* bhh1 = (const float*)d_in[10];
  const float* Wn   = (const float*)d_in[11];
  const float* bn   = (const float*)d_in[12];
  const float* Wd   = (const float*)d_in[13];
  const float* bd   = (const float*)d_in[14];
  const float* Wg   = (const float*)d_in[15];
  const float* bg   = (const float*)d_in[16];

  if (ws_size < WS_NEEDED) return;  // fail loudly (poisoned output) rather than corrupt

  char* ws = (char*)d_ws;
  uint32_t* flags = (uint32_t*)(ws + FLAGS_OFF);
  uint32_t* pub0  = (uint32_t*)(ws + PUB0_OFF);
  uint32_t* pub1  = (uint32_t*)(ws + PUB1_OFF);
  float*    bp    = (float*)(ws + BP_OFF);
  uint16_t* BW    = (uint16_t*)(ws + BLOB_OFF);

  gru_init1<<<768, 256, 0, stream>>>(Wih0, Wn, Wd, Wg, bn, bd, bg, bih0, BW, bp);
  gru_init2<<<992, 256, 0, stream>>>(Wih0, Whh0, Wih1, Whh1, Wn, Wd, Wg, flags, BW);
  gru_main <<<128, 256, LDS_TOTAL, stream>>>(x0, bih0, bhh0, bih1, bhh1, bn, bd, bg, bp,
                                             BW, flags, pub0, pub1, (float*)d_out);
}